// Round 1
// baseline (144.943 us; speedup 1.0000x reference)
//
#include <hip/hip_runtime.h>

// AffineGPT2Attention: B=4, S=1024, D=1024, H=16, Dh=64
// Pipeline: cast hs->bf16; transpose+cast weights; QKV GEMM (bf16 MFMA, scatter
// epilogue to Q[b][h][s][d], K[b][h][s][d], Vt[b][h][d][s]); flash attention
// (swapped QK^T); proj GEMM with bias+affine epilogue -> f32 out.

typedef __attribute__((ext_vector_type(4))) float  fx4;
typedef __attribute__((ext_vector_type(4))) short  sx4;
typedef __attribute__((ext_vector_type(8))) short  sx8;
typedef __attribute__((ext_vector_type(4))) float  f32x4;
typedef __attribute__((ext_vector_type(8))) __bf16 bf16x8;

#define DEVI static __device__ __forceinline__

DEVI short f2bf(float f) {  // f32 -> bf16 (RNE)
  unsigned u = __builtin_bit_cast(unsigned, f);
  u = (u + 0x7FFFu + ((u >> 16) & 1u)) >> 16;
  return (short)u;
}

DEVI fx4 mfma16(sx8 a, sx8 b, fx4 c) {
  return __builtin_amdgcn_mfma_f32_16x16x32_bf16(
      __builtin_bit_cast(bf16x8, a), __builtin_bit_cast(bf16x8, b), c, 0, 0, 0);
}

DEVI void gl_lds16(const void* g, void* l) {  // async global->LDS, 16B/lane
  __builtin_amdgcn_global_load_lds(
      (const __attribute__((address_space(1))) void*)g,
      (__attribute__((address_space(3))) void*)l, 16, 0, 0);
}

// ---------------- elementwise f32 -> bf16 cast (vectorized) ----------------
__global__ __launch_bounds__(256) void cast_bf16(const float* __restrict__ in,
                                                 short* __restrict__ out, int n4) {
  int i = blockIdx.x * blockDim.x + threadIdx.x;
  if (i < n4) {
    f32x4 v = *(const f32x4*)&in[(size_t)i * 4];
    sx4 o;
#pragma unroll
    for (int j = 0; j < 4; ++j) o[j] = f2bf(v[j]);
    *(sx4*)&out[(size_t)i * 4] = o;
  }
}

// ---------------- transpose + cast: in[R][C] f32 -> out[C][R] bf16 ----------
__global__ __launch_bounds__(256) void transpose_bf16(const float* __restrict__ in,
                                                      short* __restrict__ out,
                                                      int R, int C) {
  __shared__ float t[32][33];
  int tx = threadIdx.x & 31, ty = threadIdx.x >> 5;
  int r0 = blockIdx.y * 32, c0 = blockIdx.x * 32;
#pragma unroll
  for (int i = 0; i < 4; ++i)
    t[ty + i * 8][tx] = in[(size_t)(r0 + ty + i * 8) * C + c0 + tx];
  __syncthreads();
#pragma unroll
  for (int i = 0; i < 4; ++i)
    out[(size_t)(c0 + ty + i * 8) * R + r0 + tx] = f2bf(t[tx][ty + i * 8]);
}

// ---------------- GEMM: C[M][N] = A[M][K] @ Bt[N][K]^T ----------------------
// BM=BN=128, BK=64, 4 waves (2x2), each wave 64x64 = 4x4 frags of 16x16x32.
// EPI 0: qkv scatter epilogue (+bias). EPI 1: proj (+bias, affine) -> f32.
template <int EPI>
__global__ __launch_bounds__(256) void gemm_bt(
    const short* __restrict__ A, const short* __restrict__ Bt,
    const float* __restrict__ bias, const float* __restrict__ aw,
    const float* __restrict__ ab, short* __restrict__ Qg, short* __restrict__ Kg,
    short* __restrict__ Vtg, float* __restrict__ Out, int M, int N, int K) {
  __shared__ __align__(16) short As[128][64];
  __shared__ __align__(16) short Bs[128][64];
  const int tid = threadIdx.x, lane = tid & 63, w = tid >> 6;
  const int bn = blockIdx.x, bm = blockIdx.y;
  const int wm = w >> 1, wn = w & 1;
  const int c0 = lane & 15, g = lane >> 4;
  const int lr8 = lane >> 3;              // row within 8-row staging chunk
  const int ls8 = (lane & 7) ^ lr8;       // inverse-swizzled source slot
  fx4 acc[4][4] = {};

  for (int kt = 0; kt < K; kt += 64) {
#pragma unroll
    for (int i = 0; i < 4; ++i) {
      int r = w * 32 + i * 8;
      gl_lds16(&A[(size_t)(bm * 128 + r + lr8) * K + kt + ls8 * 8], &As[r][0]);
      gl_lds16(&Bt[(size_t)(bn * 128 + r + lr8) * K + kt + ls8 * 8], &Bs[r][0]);
    }
    __syncthreads();
#pragma unroll
    for (int kk = 0; kk < 2; ++kk) {
      sx8 af[4], bf[4];
      int sb = kk * 4 + g;
#pragma unroll
      for (int m = 0; m < 4; ++m) {
        int row = wm * 64 + m * 16 + c0;
        af[m] = *(const sx8*)&As[row][(sb ^ (row & 7)) * 8];
      }
#pragma unroll
      for (int n = 0; n < 4; ++n) {
        int row = wn * 64 + n * 16 + c0;
        bf[n] = *(const sx8*)&Bs[row][(sb ^ (row & 7)) * 8];
      }
#pragma unroll
      for (int m = 0; m < 4; ++m)
#pragma unroll
        for (int n = 0; n < 4; ++n) acc[m][n] = mfma16(af[m], bf[n], acc[m][n]);
    }
    __syncthreads();
  }

  // epilogue: C/D layout: row = (lane>>4)*4 + r, col = lane&15 (within frag)
#pragma unroll
  for (int m = 0; m < 4; ++m) {
#pragma unroll
    for (int n = 0; n < 4; ++n) {
      int col = bn * 128 + wn * 64 + n * 16 + c0;
      int row0 = bm * 128 + wm * 64 + m * 16 + g * 4;
      if (EPI == 0) {
        float bv = bias[col];
        int b = row0 >> 10, s0 = row0 & 1023;
        if (col < 1024) {
          int h = col >> 6, d = col & 63;
          size_t base = ((size_t)(b * 16 + h) * 1024) * 64 + d;
#pragma unroll
          for (int r = 0; r < 4; ++r)
            Qg[base + (size_t)(s0 + r) * 64] = f2bf(acc[m][n][r] + bv);
        } else if (col < 2048) {
          int c = col - 1024, h = c >> 6, d = c & 63;
          size_t base = ((size_t)(b * 16 + h) * 1024) * 64 + d;
#pragma unroll
          for (int r = 0; r < 4; ++r)
            Kg[base + (size_t)(s0 + r) * 64] = f2bf(acc[m][n][r] + bv);
        } else {
          int c = col - 2048, h = c >> 6, d = c & 63;
          sx4 v;
#pragma unroll
          for (int r = 0; r < 4; ++r) v[r] = f2bf(acc[m][n][r] + bv);
          *(sx4*)&Vtg[((size_t)(b * 16 + h) * 64 + d) * 1024 + s0] = v;
        }
      } else {
        float bv = bias[col], wv = aw[col], av = ab[col];
#pragma unroll
        for (int r = 0; r < 4; ++r)
          Out[(size_t)(row0 + r) * N + col] = (acc[m][n][r] + bv) * wv + av;
      }
    }
  }
}

// ---------------- flash attention (causal), swapped QK^T --------------------
// Per block: one (b,h) and a 128-row q-tile; 4 waves x 32 q-cols each.
// S^T = K @ Q^T  (C/D: row=kv, col=q -> q is lane-local => cheap softmax)
// O^T = Vt @ P^T (C/D: row=d,  col=q)
__global__ __launch_bounds__(256) void attn_kernel(const short* __restrict__ Qg,
                                                   const short* __restrict__ Kg,
                                                   const short* __restrict__ Vtg,
                                                   short* __restrict__ AO) {
  __shared__ __align__(16) short Ks[128][64];
  __shared__ __align__(16) short Vts[64][128];
  __shared__ __align__(16) short Ps[4][32 * 128];
  const int tid = threadIdx.x, lane = tid & 63, w = tid >> 6;
  const int bid = blockIdx.x;
  const int qt = bid & 7, h = (bid >> 3) & 15, b = bid >> 7;
  const int c0 = lane & 15, g = lane >> 4;
  const int lr8 = lane >> 3, ls8 = (lane & 7) ^ lr8;
  const int lr16 = lane >> 4, lp16 = lane & 15;
  const size_t bh = (size_t)(b * 16 + h);
  const short* Qp = Qg + bh * 1024 * 64;
  const short* Kp = Kg + bh * 1024 * 64;
  const short* Vp = Vtg + bh * 64 * 1024;
  const int qg0 = qt * 128 + w * 32;
  short* pbase = &Ps[w][0];

  sx8 qf[2][2];  // B-frags of Q: col=q (lane&15), k=d ((lane>>4)*8+j)
#pragma unroll
  for (int n = 0; n < 2; ++n)
#pragma unroll
    for (int kk = 0; kk < 2; ++kk)
      qf[n][kk] = *(const sx8*)&Qp[(size_t)(qg0 + n * 16 + c0) * 64 + kk * 32 + g * 8];

  fx4 o[4][2] = {};
  float mrun[2] = {-1e30f, -1e30f}, lrun[2] = {0.f, 0.f};
  const float L2E = 1.4426950408889634f;

  for (int kvt = 0; kvt <= qt; ++kvt) {
    const int kv0 = kvt * 128;
#pragma unroll
    for (int i = 0; i < 4; ++i) {
      int r = w * 32 + i * 8;
      gl_lds16(&Kp[(size_t)(kv0 + r + lr8) * 64 + ls8 * 8], &Ks[r][0]);
    }
#pragma unroll
    for (int i = 0; i < 4; ++i) {
      int d = w * 16 + i * 4 + lr16;
      int ss = lp16 ^ (d & 15);
      gl_lds16(&Vp[(size_t)d * 1024 + kv0 + ss * 8], &Vts[w * 16 + i * 4][0]);
    }
    __syncthreads();

    // S^T = K @ Q^T : 8 kv-frags x 2 q-frags
    fx4 st[8][2];
#pragma unroll
    for (int mf = 0; mf < 8; ++mf) {
      int row = mf * 16 + c0;
      sx8 kf0 = *(const sx8*)&Ks[row][((0 + g) ^ (row & 7)) * 8];
      sx8 kf1 = *(const sx8*)&Ks[row][((4 + g) ^ (row & 7)) * 8];
#pragma unroll
      for (int n = 0; n < 2; ++n) {
        fx4 z = {0.f, 0.f, 0.f, 0.f};
        z = mfma16(kf0, qf[n][0], z);
        st[mf][n] = mfma16(kf1, qf[n][1], z);
      }
    }

    // online softmax (per lane: fixed q per n)
#pragma unroll
    for (int n = 0; n < 2; ++n) {
      int q_glob = qg0 + n * 16 + c0;
      float pmax = -1e30f;
#pragma unroll
      for (int mf = 0; mf < 8; ++mf)
#pragma unroll
        for (int r = 0; r < 4; ++r) {
          int kv = kv0 + mf * 16 + g * 4 + r;
          float z = st[mf][n][r] * 0.125f;
          z = (kv > q_glob) ? -1e30f : z;
          st[mf][n][r] = z;
          pmax = fmaxf(pmax, z);
        }
      pmax = fmaxf(pmax, __shfl_xor(pmax, 16));
      pmax = fmaxf(pmax, __shfl_xor(pmax, 32));
      float mnew = fmaxf(mrun[n], pmax);
      float alpha = exp2f((mrun[n] - mnew) * L2E);
      float psum = 0.f;
#pragma unroll
      for (int mf = 0; mf < 8; ++mf)
#pragma unroll
        for (int r = 0; r < 4; ++r) {
          float p = exp2f((st[mf][n][r] - mnew) * L2E);
          st[mf][n][r] = p;
          psum += p;
        }
      psum += __shfl_xor(psum, 16);
      psum += __shfl_xor(psum, 32);
      lrun[n] = lrun[n] * alpha + psum;
      mrun[n] = mnew;
#pragma unroll
      for (int mf = 0; mf < 4; ++mf) o[mf][n] *= alpha;
      // P -> LDS (bf16), row=q-local, swizzled elem ^= (q&15)*8
      int ql = n * 16 + c0;
#pragma unroll
      for (int mf = 0; mf < 8; ++mf) {
        sx4 pv;
#pragma unroll
        for (int r = 0; r < 4; ++r) pv[r] = f2bf(st[mf][n][r]);
        *(sx4*)&pbase[ql * 128 + ((mf * 16 + g * 4) ^ (c0 * 8))] = pv;
      }
    }

    // O^T += Vt @ P^T : 4 d-frags x 2 q-frags x 4 k-steps
#pragma unroll
    for (int kk = 0; kk < 4; ++kk) {
      sx8 pbf[2], vaf[4];
#pragma unroll
      for (int n = 0; n < 2; ++n) {
        int ql = n * 16 + c0;
        pbf[n] = *(const sx8*)&pbase[ql * 128 + (((kk * 4 + g) * 8) ^ (c0 * 8))];
      }
#pragma unroll
      for (int mf = 0; mf < 4; ++mf) {
        int row = mf * 16 + c0;
        vaf[mf] = *(const sx8*)&Vts[row][((kk * 4 + g) ^ (row & 15)) * 8];
      }
#pragma unroll
      for (int mf = 0; mf < 4; ++mf)
#pragma unroll
        for (int n = 0; n < 2; ++n) o[mf][n] = mfma16(vaf[mf], pbf[n], o[mf][n]);
    }
    __syncthreads();
  }

  // store O^T -> attn_out[b][s=q][h*64+d] (merge heads), bf16
#pragma unroll
  for (int n = 0; n < 2; ++n) {
    float inv = 1.0f / lrun[n];
    int q = qg0 + n * 16 + c0;
#pragma unroll
    for (int mf = 0; mf < 4; ++mf) {
      sx4 v;
#pragma unroll
      for (int r = 0; r < 4; ++r) v[r] = f2bf(o[mf][n][r] * inv);
      int d0 = mf * 16 + g * 4;
      *(sx4*)&AO[((size_t)(b * 1024 + q)) * 1024 + h * 64 + d0] = v;
    }
  }
}

// ---------------- launch ----------------------------------------------------
extern "C" void kernel_launch(void* const* d_in, const int* in_sizes, int n_in,
                              void* d_out, int out_size, void* d_ws, size_t ws_size,
                              hipStream_t stream) {
  const float* hs  = (const float*)d_in[0];
  const float* caw = (const float*)d_in[1];
  const float* cab = (const float*)d_in[2];
  const float* cpw = (const float*)d_in[3];
  const float* cpb = (const float*)d_in[4];
  const float* afw = (const float*)d_in[5];
  const float* afb = (const float*)d_in[6];
  float* out = (float*)d_out;
  char* ws = (char*)d_ws;

  // workspace layout (40 MB): hsb/ao overlap at [0,8MB)
  short* hsb    = (short*)(ws);                    // [4096][1024] bf16 (dead after gemm1)
  short* ao     = (short*)(ws);                    // [4096][1024] bf16 (attn out)
  short* wqkvt  = (short*)(ws + ((size_t)8  << 20));  // [3072][1024] bf16
  short* wprojt = (short*)(ws + ((size_t)14 << 20));  // [1024][1024] bf16
  short* Qg     = (short*)(ws + ((size_t)16 << 20));  // [4][16][1024][64]
  short* Kg     = (short*)(ws + ((size_t)24 << 20));  // [4][16][1024][64]
  short* Vtg    = (short*)(ws + ((size_t)32 << 20));  // [4][16][64][1024]

  cast_bf16<<<4096, 256, 0, stream>>>(hs, hsb, 1048576);
  transpose_bf16<<<dim3(96, 32), 256, 0, stream>>>(caw, wqkvt, 1024, 3072);
  transpose_bf16<<<dim3(32, 32), 256, 0, stream>>>(cpw, wprojt, 1024, 1024);
  gemm_bt<0><<<dim3(24, 32), 256, 0, stream>>>(hsb, wqkvt, cab, nullptr, nullptr,
                                               Qg, Kg, Vtg, nullptr, 4096, 3072, 1024);
  attn_kernel<<<512, 256, 0, stream>>>(Qg, Kg, Vtg, ao);
  gemm_bt<1><<<dim3(8, 32), 256, 0, stream>>>(ao, wprojt, cpb, afw, afb,
                                              nullptr, nullptr, nullptr, out, 4096, 1024, 1024);
}

// Round 2
// 133.436 us; speedup vs baseline: 1.0862x; 1.0862x over previous
//
#include <hip/hip_runtime.h>

// AffineGPT2Attention: B=4, S=1024, D=1024, H=16, Dh=64
// Pipeline: cast hs->bf16; transpose+cast weights; QKV GEMM (bf16 MFMA, scatter
// epilogue to Q[b][h][s][d], K[b][h][s][d], Vt[b][h][d][s]); flash attention
// (swapped QK^T, barrier-free, direct-global K/V frags); proj GEMM with
// bias+affine epilogue -> f32 out.

typedef __attribute__((ext_vector_type(4))) float  fx4;
typedef __attribute__((ext_vector_type(4))) short  sx4;
typedef __attribute__((ext_vector_type(8))) short  sx8;
typedef __attribute__((ext_vector_type(4))) float  f32x4;
typedef __attribute__((ext_vector_type(8))) __bf16 bf16x8;

#define DEVI static __device__ __forceinline__

DEVI short f2bf(float f) {  // f32 -> bf16 (RNE)
  unsigned u = __builtin_bit_cast(unsigned, f);
  u = (u + 0x7FFFu + ((u >> 16) & 1u)) >> 16;
  return (short)u;
}

DEVI fx4 mfma16(sx8 a, sx8 b, fx4 c) {
  return __builtin_amdgcn_mfma_f32_16x16x32_bf16(
      __builtin_bit_cast(bf16x8, a), __builtin_bit_cast(bf16x8, b), c, 0, 0, 0);
}

DEVI void gl_lds16(const void* g, void* l) {  // async global->LDS, 16B/lane
  __builtin_amdgcn_global_load_lds(
      (const __attribute__((address_space(1))) void*)g,
      (__attribute__((address_space(3))) void*)l, 16, 0, 0);
}

// ---------------- elementwise f32 -> bf16 cast (vectorized) ----------------
__global__ __launch_bounds__(256) void cast_bf16(const float* __restrict__ in,
                                                 short* __restrict__ out, int n4) {
  int i = blockIdx.x * blockDim.x + threadIdx.x;
  if (i < n4) {
    f32x4 v = *(const f32x4*)&in[(size_t)i * 4];
    sx4 o;
#pragma unroll
    for (int j = 0; j < 4; ++j) o[j] = f2bf(v[j]);
    *(sx4*)&out[(size_t)i * 4] = o;
  }
}

// ---------------- transpose + cast: in[R][C] f32 -> out[C][R] bf16 ----------
__global__ __launch_bounds__(256) void transpose_bf16(const float* __restrict__ in,
                                                      short* __restrict__ out,
                                                      int R, int C) {
  __shared__ float t[32][33];
  int tx = threadIdx.x & 31, ty = threadIdx.x >> 5;
  int r0 = blockIdx.y * 32, c0 = blockIdx.x * 32;
#pragma unroll
  for (int i = 0; i < 4; ++i)
    t[ty + i * 8][tx] = in[(size_t)(r0 + ty + i * 8) * C + c0 + tx];
  __syncthreads();
#pragma unroll
  for (int i = 0; i < 4; ++i)
    out[(size_t)(c0 + ty + i * 8) * R + r0 + tx] = f2bf(t[tx][ty + i * 8]);
}

// ---------------- GEMM: C[M][N] = A[M][K] @ Bt[N][K]^T ----------------------
// BM=BN=128, BK=64, 4 waves (2x2), each wave 64x64 = 4x4 frags of 16x16x32.
// EPI 0: qkv scatter epilogue (+bias). EPI 1: proj (+bias, affine) -> f32.
template <int EPI>
__global__ __launch_bounds__(256) void gemm_bt(
    const short* __restrict__ A, const short* __restrict__ Bt,
    const float* __restrict__ bias, const float* __restrict__ aw,
    const float* __restrict__ ab, short* __restrict__ Qg, short* __restrict__ Kg,
    short* __restrict__ Vtg, float* __restrict__ Out, int M, int N, int K) {
  __shared__ __align__(16) short As[128][64];
  __shared__ __align__(16) short Bs[128][64];
  const int tid = threadIdx.x, lane = tid & 63, w = tid >> 6;
  const int bn = blockIdx.x, bm = blockIdx.y;
  const int wm = w >> 1, wn = w & 1;
  const int c0 = lane & 15, g = lane >> 4;
  const int lr8 = lane >> 3;              // row within 8-row staging chunk
  const int ls8 = (lane & 7) ^ lr8;       // inverse-swizzled source slot
  fx4 acc[4][4] = {};

  for (int kt = 0; kt < K; kt += 64) {
#pragma unroll
    for (int i = 0; i < 4; ++i) {
      int r = w * 32 + i * 8;
      gl_lds16(&A[(size_t)(bm * 128 + r + lr8) * K + kt + ls8 * 8], &As[r][0]);
      gl_lds16(&Bt[(size_t)(bn * 128 + r + lr8) * K + kt + ls8 * 8], &Bs[r][0]);
    }
    __syncthreads();
#pragma unroll
    for (int kk = 0; kk < 2; ++kk) {
      sx8 af[4], bf[4];
      int sb = kk * 4 + g;
#pragma unroll
      for (int m = 0; m < 4; ++m) {
        int row = wm * 64 + m * 16 + c0;
        af[m] = *(const sx8*)&As[row][(sb ^ (row & 7)) * 8];
      }
#pragma unroll
      for (int n = 0; n < 4; ++n) {
        int row = wn * 64 + n * 16 + c0;
        bf[n] = *(const sx8*)&Bs[row][(sb ^ (row & 7)) * 8];
      }
#pragma unroll
      for (int m = 0; m < 4; ++m)
#pragma unroll
        for (int n = 0; n < 4; ++n) acc[m][n] = mfma16(af[m], bf[n], acc[m][n]);
    }
    __syncthreads();
  }

  // epilogue: C/D layout: row = (lane>>4)*4 + r, col = lane&15 (within frag)
#pragma unroll
  for (int m = 0; m < 4; ++m) {
#pragma unroll
    for (int n = 0; n < 4; ++n) {
      int col = bn * 128 + wn * 64 + n * 16 + c0;
      int row0 = bm * 128 + wm * 64 + m * 16 + g * 4;
      if (EPI == 0) {
        float bv = bias[col];
        int b = row0 >> 10, s0 = row0 & 1023;
        if (col < 1024) {
          int h = col >> 6, d = col & 63;
          size_t base = ((size_t)(b * 16 + h) * 1024) * 64 + d;
#pragma unroll
          for (int r = 0; r < 4; ++r)
            Qg[base + (size_t)(s0 + r) * 64] = f2bf(acc[m][n][r] + bv);
        } else if (col < 2048) {
          int c = col - 1024, h = c >> 6, d = c & 63;
          size_t base = ((size_t)(b * 16 + h) * 1024) * 64 + d;
#pragma unroll
          for (int r = 0; r < 4; ++r)
            Kg[base + (size_t)(s0 + r) * 64] = f2bf(acc[m][n][r] + bv);
        } else {
          int c = col - 2048, h = c >> 6, d = c & 63;
          sx4 v;
#pragma unroll
          for (int r = 0; r < 4; ++r) v[r] = f2bf(acc[m][n][r] + bv);
          *(sx4*)&Vtg[((size_t)(b * 16 + h) * 64 + d) * 1024 + s0] = v;
        }
      } else {
        float bv = bias[col], wv = aw[col], av = ab[col];
#pragma unroll
        for (int r = 0; r < 4; ++r)
          Out[(size_t)(row0 + r) * N + col] = (acc[m][n][r] + bv) * wv + av;
      }
    }
  }
}

// ---------------- flash attention (causal), barrier-free --------------------
// Grid 512: bid = p*64 + bh, p in 0..7. Block = 4 independent waves; wave w
// handles q-slice j = {p, 15-p, 16+p, 31-p}[w] (32 q rows) -> every block
// does exactly 34 kv-tile units (perfect balance). KVBLK=64.
// K/V frags loaded直接 from global (L2-resident); only P goes through LDS.
// S^T = K @ Q^T  (C/D: row=kv, col=q -> q lane-local => cheap softmax)
// O^T = Vt @ P^T (C/D: row=d,  col=q)
__global__ __launch_bounds__(256, 3) void attn_kernel(const short* __restrict__ Qg,
                                                      const short* __restrict__ Kg,
                                                      const short* __restrict__ Vtg,
                                                      short* __restrict__ AO) {
  __shared__ __align__(16) short Ps[4][32 * 64];  // 16 KB total
  const int tid = threadIdx.x, lane = tid & 63, w = tid >> 6;
  const int bid = blockIdx.x;
  const int p = bid >> 6, bh = bid & 63;
  const int b = bh >> 4, h = bh & 15;
  const int c0 = lane & 15, g = lane >> 4;
  const int j = ((w & 2) << 3) | ((w & 1) ? (15 - p) : p);
  const int q0 = j << 5;
  const short* Qp = Qg + (size_t)bh * 65536;
  const short* Kp = Kg + (size_t)bh * 65536;
  const short* Vp = Vtg + (size_t)bh * 65536;
  short* pbase = &Ps[w][0];
  const int s8 = (c0 & 7) * 8;  // P swizzle
  const float L2E = 1.4426950408889634f;

  sx8 qf[2][2];  // B-frags of Q: col=q (lane&15), k=d ((lane>>4)*8+j)
#pragma unroll
  for (int n = 0; n < 2; ++n)
#pragma unroll
    for (int kk = 0; kk < 2; ++kk)
      qf[n][kk] = *(const sx8*)&Qp[(size_t)(q0 + n * 16 + c0) * 64 + kk * 32 + g * 8];

  fx4 o[4][2] = {};
  float mrun[2] = {-1e30f, -1e30f}, lrun[2] = {0.f, 0.f};
  const int ntiles = (q0 + 95) >> 6;  // causal: kv < q0+32

  for (int kvt = 0; kvt < ntiles; ++kvt) {
    const int kv0 = kvt * 64;
    const bool domask = (kvt == ntiles - 1);

    // S^T = K @ Q^T : 4 kv-frags x 2 q-frags, K frags direct from global
    fx4 st[4][2];
#pragma unroll
    for (int mf = 0; mf < 4; ++mf) {
      const short* kr = &Kp[(size_t)(kv0 + mf * 16 + c0) * 64 + g * 8];
      sx8 kf0 = *(const sx8*)kr;
      sx8 kf1 = *(const sx8*)(kr + 32);
#pragma unroll
      for (int n = 0; n < 2; ++n) {
        fx4 z = {0.f, 0.f, 0.f, 0.f};
        z = mfma16(kf0, qf[n][0], z);
        st[mf][n] = mfma16(kf1, qf[n][1], z);
      }
    }

    // online softmax (per lane: fixed q per n)
#pragma unroll
    for (int n = 0; n < 2; ++n) {
      const int q_glob = q0 + n * 16 + c0;
      float pmax = -1e30f;
#pragma unroll
      for (int mf = 0; mf < 4; ++mf)
#pragma unroll
        for (int r = 0; r < 4; ++r) {
          float z = st[mf][n][r] * 0.125f;
          if (domask) {
            int kv = kv0 + mf * 16 + g * 4 + r;
            z = (kv > q_glob) ? -1e30f : z;
          }
          st[mf][n][r] = z;
          pmax = fmaxf(pmax, z);
        }
      pmax = fmaxf(pmax, __shfl_xor(pmax, 16));
      pmax = fmaxf(pmax, __shfl_xor(pmax, 32));
      float mnew = fmaxf(mrun[n], pmax);
      float alpha = exp2f((mrun[n] - mnew) * L2E);
      float psum = 0.f;
#pragma unroll
      for (int mf = 0; mf < 4; ++mf) {
        sx4 pv;
#pragma unroll
        for (int r = 0; r < 4; ++r) {
          float pp = exp2f((st[mf][n][r] - mnew) * L2E);
          psum += pp;
          pv[r] = f2bf(pp);
        }
        *(sx4*)&pbase[(n * 16 + c0) * 64 + ((mf * 16 + g * 4) ^ s8)] = pv;
      }
      psum += __shfl_xor(psum, 16);
      psum += __shfl_xor(psum, 32);
      lrun[n] = lrun[n] * alpha + psum;
      mrun[n] = mnew;
#pragma unroll
      for (int mf = 0; mf < 4; ++mf) o[mf][n] *= alpha;
    }

    // O^T += Vt @ P^T : 4 d-frags x 2 q-frags x 2 k-steps, V direct global
#pragma unroll
    for (int kk = 0; kk < 2; ++kk) {
      sx8 pbf[2];
#pragma unroll
      for (int n = 0; n < 2; ++n)
        pbf[n] = *(const sx8*)&pbase[(n * 16 + c0) * 64 + ((kk * 32 + g * 8) ^ s8)];
#pragma unroll
      for (int mf = 0; mf < 4; ++mf) {
        sx8 vaf = *(const sx8*)&Vp[(size_t)(mf * 16 + c0) * 1024 + kv0 + kk * 32 + g * 8];
#pragma unroll
        for (int n = 0; n < 2; ++n) o[mf][n] = mfma16(vaf, pbf[n], o[mf][n]);
      }
    }
  }

  // store O^T -> attn_out[b][s=q][h*64+d] (merge heads), bf16
#pragma unroll
  for (int n = 0; n < 2; ++n) {
    float inv = 1.0f / lrun[n];
    int q = q0 + n * 16 + c0;
#pragma unroll
    for (int mf = 0; mf < 4; ++mf) {
      sx4 v;
#pragma unroll
      for (int r = 0; r < 4; ++r) v[r] = f2bf(o[mf][n][r] * inv);
      int d0 = mf * 16 + g * 4;
      *(sx4*)&AO[((size_t)(b * 1024 + q)) * 1024 + h * 64 + d0] = v;
    }
  }
}

// ---------------- launch ----------------------------------------------------
extern "C" void kernel_launch(void* const* d_in, const int* in_sizes, int n_in,
                              void* d_out, int out_size, void* d_ws, size_t ws_size,
                              hipStream_t stream) {
  const float* hs  = (const float*)d_in[0];
  const float* caw = (const float*)d_in[1];
  const float* cab = (const float*)d_in[2];
  const float* cpw = (const float*)d_in[3];
  const float* cpb = (const float*)d_in[4];
  const float* afw = (const float*)d_in[5];
  const float* afb = (const float*)d_in[6];
  float* out = (float*)d_out;
  char* ws = (char*)d_ws;

  // workspace layout (40 MB): hsb/ao overlap at [0,8MB)
  short* hsb    = (short*)(ws);                    // [4096][1024] bf16 (dead after gemm1)
  short* ao     = (short*)(ws);                    // [4096][1024] bf16 (attn out)
  short* wqkvt  = (short*)(ws + ((size_t)8  << 20));  // [3072][1024] bf16
  short* wprojt = (short*)(ws + ((size_t)14 << 20));  // [1024][1024] bf16
  short* Qg     = (short*)(ws + ((size_t)16 << 20));  // [4][16][1024][64]
  short* Kg     = (short*)(ws + ((size_t)24 << 20));  // [4][16][1024][64]
  short* Vtg    = (short*)(ws + ((size_t)32 << 20));  // [4][16][64][1024]

  cast_bf16<<<4096, 256, 0, stream>>>(hs, hsb, 1048576);
  transpose_bf16<<<dim3(96, 32), 256, 0, stream>>>(caw, wqkvt, 1024, 3072);
  transpose_bf16<<<dim3(32, 32), 256, 0, stream>>>(cpw, wprojt, 1024, 1024);
  gemm_bt<0><<<dim3(24, 32), 256, 0, stream>>>(hsb, wqkvt, cab, nullptr, nullptr,
                                               Qg, Kg, Vtg, nullptr, 4096, 3072, 1024);
  attn_kernel<<<512, 256, 0, stream>>>(Qg, Kg, Vtg, ao);
  gemm_bt<1><<<dim3(8, 32), 256, 0, stream>>>(ao, wprojt, cpb, afw, afb,
                                              nullptr, nullptr, nullptr, out, 4096, 1024, 1024);
}

// Round 3
// 118.613 us; speedup vs baseline: 1.2220x; 1.1250x over previous
//
#include <hip/hip_runtime.h>

// AffineGPT2Attention: B=4, S=1024, D=1024, H=16, Dh=64
// Pipeline: cast hs->bf16; transpose+cast weights; QKV GEMM (bf16 MFMA, scatter
// epilogue to Q[b][h][s][d] (pre-scaled by 0.125*log2e), K[b][h][s][d],
// Vt[b][h][d][s]); flash attention (swapped QK^T, barrier-free, reg-double-
// buffered direct-global K/V frags); proj GEMM with bias+affine -> f32 out.

typedef __attribute__((ext_vector_type(4))) float  fx4;
typedef __attribute__((ext_vector_type(4))) short  sx4;
typedef __attribute__((ext_vector_type(8))) short  sx8;
typedef __attribute__((ext_vector_type(4))) float  f32x4;
typedef __attribute__((ext_vector_type(8))) __bf16 bf16x8;

#define DEVI static __device__ __forceinline__

DEVI short f2bf(float f) {  // f32 -> bf16 (RNE)
  unsigned u = __builtin_bit_cast(unsigned, f);
  u = (u + 0x7FFFu + ((u >> 16) & 1u)) >> 16;
  return (short)u;
}

DEVI fx4 mfma16(sx8 a, sx8 b, fx4 c) {
  return __builtin_amdgcn_mfma_f32_16x16x32_bf16(
      __builtin_bit_cast(bf16x8, a), __builtin_bit_cast(bf16x8, b), c, 0, 0, 0);
}

DEVI void gl_lds16(const void* g, void* l) {  // async global->LDS, 16B/lane
  __builtin_amdgcn_global_load_lds(
      (const __attribute__((address_space(1))) void*)g,
      (__attribute__((address_space(3))) void*)l, 16, 0, 0);
}

// ---------------- elementwise f32 -> bf16 cast (vectorized) ----------------
__global__ __launch_bounds__(256) void cast_bf16(const float* __restrict__ in,
                                                 short* __restrict__ out, int n4) {
  int i = blockIdx.x * blockDim.x + threadIdx.x;
  if (i < n4) {
    f32x4 v = *(const f32x4*)&in[(size_t)i * 4];
    sx4 o;
#pragma unroll
    for (int j = 0; j < 4; ++j) o[j] = f2bf(v[j]);
    *(sx4*)&out[(size_t)i * 4] = o;
  }
}

// ---------------- transpose + cast: in[R][C] f32 -> out[C][R] bf16 ----------
__global__ __launch_bounds__(256) void transpose_bf16(const float* __restrict__ in,
                                                      short* __restrict__ out,
                                                      int R, int C) {
  __shared__ float t[32][33];
  int tx = threadIdx.x & 31, ty = threadIdx.x >> 5;
  int r0 = blockIdx.y * 32, c0 = blockIdx.x * 32;
#pragma unroll
  for (int i = 0; i < 4; ++i)
    t[ty + i * 8][tx] = in[(size_t)(r0 + ty + i * 8) * C + c0 + tx];
  __syncthreads();
#pragma unroll
  for (int i = 0; i < 4; ++i)
    out[(size_t)(c0 + ty + i * 8) * R + r0 + tx] = f2bf(t[tx][ty + i * 8]);
}

// ---------------- GEMM: C[M][N] = A[M][K] @ Bt[N][K]^T ----------------------
// BM=BN=128, BK=64, 4 waves (2x2), each wave 64x64 = 4x4 frags of 16x16x32.
// EPI 0: qkv scatter epilogue (+bias, Q pre-scaled). EPI 1: proj (+bias,affine).
template <int EPI>
__global__ __launch_bounds__(256) void gemm_bt(
    const short* __restrict__ A, const short* __restrict__ Bt,
    const float* __restrict__ bias, const float* __restrict__ aw,
    const float* __restrict__ ab, short* __restrict__ Qg, short* __restrict__ Kg,
    short* __restrict__ Vtg, float* __restrict__ Out, int M, int N, int K) {
  __shared__ __align__(16) short As[128][64];
  __shared__ __align__(16) short Bs[128][64];
  const int tid = threadIdx.x, lane = tid & 63, w = tid >> 6;
  const int bn = blockIdx.x, bm = blockIdx.y;
  const int wm = w >> 1, wn = w & 1;
  const int c0 = lane & 15, g = lane >> 4;
  const int lr8 = lane >> 3;              // row within 8-row staging chunk
  const int ls8 = (lane & 7) ^ lr8;       // inverse-swizzled source slot
  fx4 acc[4][4] = {};

  for (int kt = 0; kt < K; kt += 64) {
#pragma unroll
    for (int i = 0; i < 4; ++i) {
      int r = w * 32 + i * 8;
      gl_lds16(&A[(size_t)(bm * 128 + r + lr8) * K + kt + ls8 * 8], &As[r][0]);
      gl_lds16(&Bt[(size_t)(bn * 128 + r + lr8) * K + kt + ls8 * 8], &Bs[r][0]);
    }
    __syncthreads();
#pragma unroll
    for (int kk = 0; kk < 2; ++kk) {
      sx8 af[4], bf[4];
      int sb = kk * 4 + g;
#pragma unroll
      for (int m = 0; m < 4; ++m) {
        int row = wm * 64 + m * 16 + c0;
        af[m] = *(const sx8*)&As[row][(sb ^ (row & 7)) * 8];
      }
#pragma unroll
      for (int n = 0; n < 4; ++n) {
        int row = wn * 64 + n * 16 + c0;
        bf[n] = *(const sx8*)&Bs[row][(sb ^ (row & 7)) * 8];
      }
#pragma unroll
      for (int m = 0; m < 4; ++m)
#pragma unroll
        for (int n = 0; n < 4; ++n) acc[m][n] = mfma16(af[m], bf[n], acc[m][n]);
    }
    __syncthreads();
  }

  // epilogue: C/D layout: row = (lane>>4)*4 + r, col = lane&15 (within frag)
  const float SCALE_Q = 0.125f * 1.4426950408889634f;  // fold 1/sqrt(64)*log2e
#pragma unroll
  for (int m = 0; m < 4; ++m) {
#pragma unroll
    for (int n = 0; n < 4; ++n) {
      int col = bn * 128 + wn * 64 + n * 16 + c0;
      int row0 = bm * 128 + wm * 64 + m * 16 + g * 4;
      if (EPI == 0) {
        float bv = bias[col];
        int b = row0 >> 10, s0 = row0 & 1023;
        if (col < 1024) {
          int h = col >> 6, d = col & 63;
          size_t base = ((size_t)(b * 16 + h) * 1024) * 64 + d;
#pragma unroll
          for (int r = 0; r < 4; ++r)
            Qg[base + (size_t)(s0 + r) * 64] = f2bf((acc[m][n][r] + bv) * SCALE_Q);
        } else if (col < 2048) {
          int c = col - 1024, h = c >> 6, d = c & 63;
          size_t base = ((size_t)(b * 16 + h) * 1024) * 64 + d;
#pragma unroll
          for (int r = 0; r < 4; ++r)
            Kg[base + (size_t)(s0 + r) * 64] = f2bf(acc[m][n][r] + bv);
        } else {
          int c = col - 2048, h = c >> 6, d = c & 63;
          sx4 v;
#pragma unroll
          for (int r = 0; r < 4; ++r) v[r] = f2bf(acc[m][n][r] + bv);
          *(sx4*)&Vtg[((size_t)(b * 16 + h) * 64 + d) * 1024 + s0] = v;
        }
      } else {
        float bv = bias[col], wv = aw[col], av = ab[col];
#pragma unroll
        for (int r = 0; r < 4; ++r)
          Out[(size_t)(row0 + r) * N + col] = (acc[m][n][r] + bv) * wv + av;
      }
    }
  }
}

// ---------------- flash attention (causal), barrier-free --------------------
// Grid 512: bid = p*64 + bh. Block = 4 independent waves; wave w handles
// q-slice j = {p, 15-p, 16+p, 31-p}[w] (32 q rows) -> perfect balance.
// KVBLK=64. K frags register-double-buffered (kA/kB), V single-buffered,
// all loaded direct from global (L2-resident). Only P goes through LDS.
// Scores arrive pre-scaled (Q folded with 0.125*log2e) -> p = exp2(z - m).
__global__ __launch_bounds__(256, 2) void attn_kernel(const short* __restrict__ Qg,
                                                      const short* __restrict__ Kg,
                                                      const short* __restrict__ Vtg,
                                                      short* __restrict__ AO) {
  __shared__ __align__(16) short Ps[4][32 * 64];  // 16 KB total
  const int tid = threadIdx.x, lane = tid & 63, w = tid >> 6;
  const int bid = blockIdx.x;
  const int p = bid >> 6, bh = bid & 63;
  const int b = bh >> 4, h = bh & 15;
  const int c0 = lane & 15, g = lane >> 4;
  const int j = ((w & 2) << 3) | ((w & 1) ? (15 - p) : p);
  const int q0 = j << 5;
  const short* Qp = Qg + (size_t)bh * 65536;
  const short* Kp = Kg + (size_t)bh * 65536;
  const short* Vp = Vtg + (size_t)bh * 65536;
  short* pbase = &Ps[w][0];
  const int s8 = (c0 & 7) * 8;  // P swizzle

  sx8 qf[2][2];  // B-frags of Q: col=q (lane&15), k=d ((lane>>4)*8+j)
#pragma unroll
  for (int n = 0; n < 2; ++n)
#pragma unroll
    for (int kk = 0; kk < 2; ++kk)
      qf[n][kk] = *(const sx8*)&Qp[(size_t)(q0 + n * 16 + c0) * 64 + kk * 32 + g * 8];

  fx4 o[4][2] = {};
  fx4 st[4][2];
  float mrun[2] = {-1e30f, -1e30f}, lrun[2] = {0.f, 0.f};
  const int ntiles = (q0 + 95) >> 6;  // causal: kv < q0+32

  sx8 kA[4][2], kB[4][2], vC[4][2];

  auto LOADK = [&](sx8 (&kb)[4][2], int kv0) {
#pragma unroll
    for (int mf = 0; mf < 4; ++mf) {
      const short* kr = &Kp[(size_t)(kv0 + mf * 16 + c0) * 64 + g * 8];
      kb[mf][0] = *(const sx8*)kr;
      kb[mf][1] = *(const sx8*)(kr + 32);
    }
  };
  auto LOADV = [&](int kv0) {
#pragma unroll
    for (int mf = 0; mf < 4; ++mf) {
      const short* vr = &Vp[(size_t)(mf * 16 + c0) * 1024 + kv0 + g * 8];
      vC[mf][0] = *(const sx8*)vr;
      vC[mf][1] = *(const sx8*)(vr + 32);
    }
  };
  auto QKT = [&](sx8 (&kb)[4][2]) {
#pragma unroll
    for (int mf = 0; mf < 4; ++mf)
#pragma unroll
      for (int n = 0; n < 2; ++n) {
        fx4 z = {0.f, 0.f, 0.f, 0.f};
        z = mfma16(kb[mf][0], qf[n][0], z);
        st[mf][n] = mfma16(kb[mf][1], qf[n][1], z);
      }
  };
  auto SMPV = [&](int kvt, bool domask) {  // softmax + P->LDS + PV
    const int kv0 = kvt * 64;
#pragma unroll
    for (int n = 0; n < 2; ++n) {
      const int q_glob = q0 + n * 16 + c0;
      float pmax = -1e30f;
#pragma unroll
      for (int mf = 0; mf < 4; ++mf)
#pragma unroll
        for (int r = 0; r < 4; ++r) {
          float z = st[mf][n][r];
          if (domask) {
            int kv = kv0 + mf * 16 + g * 4 + r;
            z = (kv > q_glob) ? -1e30f : z;
            st[mf][n][r] = z;
          }
          pmax = fmaxf(pmax, z);
        }
      pmax = fmaxf(pmax, __shfl_xor(pmax, 16));
      pmax = fmaxf(pmax, __shfl_xor(pmax, 32));
      float mnew = fmaxf(mrun[n], pmax);
      float alpha = __builtin_amdgcn_exp2f(mrun[n] - mnew);
      float psum = 0.f;
#pragma unroll
      for (int mf = 0; mf < 4; ++mf) {
        sx4 pv;
#pragma unroll
        for (int r = 0; r < 4; ++r) {
          float pp = __builtin_amdgcn_exp2f(st[mf][n][r] - mnew);
          psum += pp;
          pv[r] = f2bf(pp);
        }
        *(sx4*)&pbase[(n * 16 + c0) * 64 + ((mf * 16 + g * 4) ^ s8)] = pv;
      }
      psum += __shfl_xor(psum, 16);
      psum += __shfl_xor(psum, 32);
      lrun[n] = lrun[n] * alpha + psum;
      mrun[n] = mnew;
#pragma unroll
      for (int mf = 0; mf < 4; ++mf) o[mf][n] *= alpha;
    }
#pragma unroll
    for (int kk = 0; kk < 2; ++kk) {
      sx8 pbf[2];
#pragma unroll
      for (int n = 0; n < 2; ++n)
        pbf[n] = *(const sx8*)&pbase[(n * 16 + c0) * 64 + ((kk * 32 + g * 8) ^ s8)];
#pragma unroll
      for (int mf = 0; mf < 4; ++mf)
#pragma unroll
        for (int n = 0; n < 2; ++n) o[mf][n] = mfma16(vC[mf][kk], pbf[n], o[mf][n]);
    }
  };

  LOADK(kA, 0);
  int kvt = 0;
  while (true) {
    {  // tile kvt using kA
      LOADV(kvt * 64);
      QKT(kA);
      int nx = kvt + 1;
      bool more = nx < ntiles;
      LOADK(kB, more ? nx * 64 : 0);
      SMPV(kvt, !more);
      if (!more) break;
    }
    {  // tile kvt+1 using kB
      int nx = kvt + 1;
      LOADV(nx * 64);
      QKT(kB);
      int nx2 = kvt + 2;
      bool more2 = nx2 < ntiles;
      LOADK(kA, more2 ? nx2 * 64 : 0);
      SMPV(nx, !more2);
      if (!more2) break;
    }
    kvt += 2;
  }

  // store O^T -> attn_out[b][s=q][h*64+d] (merge heads), bf16
#pragma unroll
  for (int n = 0; n < 2; ++n) {
    float inv = 1.0f / lrun[n];
    int q = q0 + n * 16 + c0;
#pragma unroll
    for (int mf = 0; mf < 4; ++mf) {
      sx4 v;
#pragma unroll
      for (int r = 0; r < 4; ++r) v[r] = f2bf(o[mf][n][r] * inv);
      int d0 = mf * 16 + g * 4;
      *(sx4*)&AO[((size_t)(b * 1024 + q)) * 1024 + h * 64 + d0] = v;
    }
  }
}

// ---------------- launch ----------------------------------------------------
extern "C" void kernel_launch(void* const* d_in, const int* in_sizes, int n_in,
                              void* d_out, int out_size, void* d_ws, size_t ws_size,
                              hipStream_t stream) {
  const float* hs  = (const float*)d_in[0];
  const float* caw = (const float*)d_in[1];
  const float* cab = (const float*)d_in[2];
  const float* cpw = (const float*)d_in[3];
  const float* cpb = (const float*)d_in[4];
  const float* afw = (const float*)d_in[5];
  const float* afb = (const float*)d_in[6];
  float* out = (float*)d_out;
  char* ws = (char*)d_ws;

  // workspace layout (40 MB): hsb/ao overlap at [0,8MB)
  short* hsb    = (short*)(ws);                    // [4096][1024] bf16 (dead after gemm1)
  short* ao     = (short*)(ws);                    // [4096][1024] bf16 (attn out)
  short* wqkvt  = (short*)(ws + ((size_t)8  << 20));  // [3072][1024] bf16
  short* wprojt = (short*)(ws + ((size_t)14 << 20));  // [1024][1024] bf16
  short* Qg     = (short*)(ws + ((size_t)16 << 20));  // [4][16][1024][64]
  short* Kg     = (short*)(ws + ((size_t)24 << 20));  // [4][16][1024][64]
  short* Vtg    = (short*)(ws + ((size_t)32 << 20));  // [4][16][64][1024]

  cast_bf16<<<4096, 256, 0, stream>>>(hs, hsb, 1048576);
  transpose_bf16<<<dim3(96, 32), 256, 0, stream>>>(caw, wqkvt, 1024, 3072);
  transpose_bf16<<<dim3(32, 32), 256, 0, stream>>>(cpw, wprojt, 1024, 1024);
  gemm_bt<0><<<dim3(24, 32), 256, 0, stream>>>(hsb, wqkvt, cab, nullptr, nullptr,
                                               Qg, Kg, Vtg, nullptr, 4096, 3072, 1024);
  attn_kernel<<<512, 256, 0, stream>>>(Qg, Kg, Vtg, ao);
  gemm_bt<1><<<dim3(8, 32), 256, 0, stream>>>(ao, wprojt, cpb, afw, afb,
                                              nullptr, nullptr, nullptr, out, 4096, 1024, 1024);
}